// Round 5
// baseline (123.041 us; speedup 1.0000x reference)
//
#include <hip/hip_runtime.h>
#include <math.h>

#define DI 1024   // model dim
#define SQ 2048   // sequence length
#define NB 2      // batch
#define NH 16     // heads
#define HD 64     // head dim
#define QSCALE 0.18033688f   // 0.125 * log2(e): folded into Q so softmax exp is raw v_exp_f32 (2^x)

typedef __attribute__((ext_vector_type(8))) short short8;
typedef __attribute__((ext_vector_type(4))) float f32x4;
typedef __attribute__((ext_vector_type(16))) float f32x16;
typedef __attribute__((ext_vector_type(2))) unsigned int uint2v;
typedef __attribute__((ext_vector_type(4))) int int4v;
typedef __attribute__((ext_vector_type(4))) unsigned short ushort4v;

static __device__ __forceinline__ unsigned short f2bf(float f) {
    union { float f; unsigned u; } v; v.f = f;
    unsigned r = v.u + 0x7FFFu + ((v.u >> 16) & 1u);  // RNE
    return (unsigned short)(r >> 16);
}
static __device__ __forceinline__ float fexp2(float x) {
    float r; asm("v_exp_f32 %0, %1" : "=v"(r) : "v"(x)); return r;
}
static __device__ __forceinline__ unsigned cvtpk(float lo, float hi) {
    unsigned r; asm("v_cvt_pk_bf16_f32 %0, %1, %2" : "=v"(r) : "v"(lo), "v"(hi)); return r;
}
static __device__ __forceinline__ void plswap(unsigned& a, unsigned& b) {
    asm volatile("v_permlane32_swap_b32 %0, %1" : "+v"(a), "+v"(b));
}
static __device__ __forceinline__ short8 pack4(unsigned a, unsigned b, unsigned c, unsigned d) {
    union { unsigned u[4]; short8 s; } x; x.u[0] = a; x.u[1] = b; x.u[2] = c; x.u[3] = d; return x.s;
}

typedef __attribute__((address_space(1))) const unsigned int gas_uint;
typedef __attribute__((address_space(3))) unsigned int las_uint;
static __device__ __forceinline__ void gload16(const void* g, void* l) {
    __builtin_amdgcn_global_load_lds((gas_uint*)g, (las_uint*)l, 16, 0, 0);
}
// Pipeline (T3/T4, race-correct per-wave-vmcnt): stage(kt+1) -> wait OWN tile-kt
// loads (vmcnt(4)) -> s_barrier (now ALL waves' tile-kt loads landed) -> compute.
// Triple-buffered LDS covers the laggard-wave write hazard (stage kt+1 overwrites
// a buffer last read at tile kt-2, already barrier-separated).
#define RAW_BARRIER() do { __builtin_amdgcn_s_barrier(); \
                           __builtin_amdgcn_sched_barrier(0); } while (0)
#define WAIT_VM4()  do { asm volatile("s_waitcnt vmcnt(4)" ::: "memory"); \
                         __builtin_amdgcn_sched_barrier(0); } while (0)
#define WAIT_VM0()  do { asm volatile("s_waitcnt vmcnt(0)" ::: "memory"); \
                         __builtin_amdgcn_sched_barrier(0); } while (0)

#define MFMA16(a, b, c) __builtin_amdgcn_mfma_f32_16x16x32_bf16(a, b, c, 0, 0, 0)
#define MFMA32(a, b, c) __builtin_amdgcn_mfma_f32_32x32x16_bf16(a, b, c, 0, 0, 0)

// ---------------------------------------------------------------- cvt x -> bf16
__global__ __launch_bounds__(256) void k_cvt_bf16(const float* __restrict__ src,
                                                  unsigned short* __restrict__ dst) {
    int i = blockIdx.x * 256 + threadIdx.x;     // 8 floats / thread
    const f32x4* s4 = (const f32x4*)src + (size_t)i * 2;
    f32x4 a = s4[0], b = s4[1];
    ushort4v o0, o1;
    o0[0] = f2bf(a[0]); o0[1] = f2bf(a[1]); o0[2] = f2bf(a[2]); o0[3] = f2bf(a[3]);
    o1[0] = f2bf(b[0]); o1[1] = f2bf(b[1]); o1[2] = f2bf(b[2]); o1[3] = f2bf(b[3]);
    *(ushort4v*)(dst + (size_t)i * 8)     = o0;
    *(ushort4v*)(dst + (size_t)i * 8 + 4) = o1;
}

// ------------------------------------- 4x: W [K][N] f32 -> Wt [N][K] bf16 (one dispatch)
__global__ __launch_bounds__(256) void k_transpose_w4(const float* __restrict__ W0, const float* __restrict__ W1,
                                                      const float* __restrict__ W2, const float* __restrict__ W3,
                                                      unsigned short* __restrict__ T0, unsigned short* __restrict__ T1,
                                                      unsigned short* __restrict__ T2, unsigned short* __restrict__ T3) {
    const float* W; unsigned short* T;
    switch (blockIdx.z) {
        case 0: W = W0; T = T0; break;
        case 1: W = W1; T = T1; break;
        case 2: W = W2; T = T2; break;
        default: W = W3; T = T3; break;
    }
    __shared__ float t[32][33];
    int tx = threadIdx.x, ty = threadIdx.y;     // block (32,8)
    int n0 = blockIdx.x * 32, k0 = blockIdx.y * 32;
#pragma unroll
    for (int j = 0; j < 32; j += 8) t[ty + j][tx] = W[(size_t)(k0 + ty + j) * DI + n0 + tx];
    __syncthreads();
#pragma unroll
    for (int j = 0; j < 32; j += 8)
        T[(size_t)(n0 + ty + j) * DI + k0 + tx] = f2bf(t[tx][ty + j]);
}

// ---------------------------------------------------------------- NT GEMM (m97 + counted vmcnt, 3-buf)
// MODE 0: fused QKV. Bt = [3*1024][1024]; which = tn>>3 routes to oK / oQ(scaled) / oV(transposed).
// MODE 2: f32 out + bias (final projection), C = oK as float*.
template <int MODE>
__global__ __launch_bounds__(256) void k_gemm(const unsigned short* __restrict__ A,
                                              const unsigned short* __restrict__ Bt,
                                              unsigned short* __restrict__ oK,
                                              unsigned short* __restrict__ oQ,
                                              unsigned short* __restrict__ oV,
                                              const float* __restrict__ bias) {
    __shared__ __align__(16) unsigned short As[3][128 * 32];   // linear, 64B rows, 3-buf
    __shared__ __align__(16) unsigned short Bs[3][128 * 32];
    const int tid = threadIdx.x, lane = tid & 63, w = tid >> 6;
    const int wr = w >> 1, wc = w & 1;
    const int tm = blockIdx.y, tn = blockIdx.x;
    const unsigned short* Abase = A  + (size_t)tm * 128 * DI;
    const unsigned short* Bbase = Bt + (size_t)tn * 128 * DI;

    auto stage = [&](int kt, int bi) {          // 4 global_load_lds per thread
#pragma unroll
        for (int i = 0; i < 2; ++i) {
            int u = tid + i * 256;              // 0..511 : row = u>>2, 16B seg = u&3
            int row = u >> 2, c8 = (u & 3) * 8;
            gload16(Abase + (size_t)row * DI + kt * 32 + c8, &As[bi][u * 8]);
            gload16(Bbase + (size_t)row * DI + kt * 32 + c8, &Bs[bi][u * 8]);
        }
    };

    f32x4 acc[4][4] = {};
    stage(0, 0);
    for (int kt = 0; kt < DI / 32; ++kt) {
        if (kt + 1 < DI / 32) { stage(kt + 1, (kt + 1) % 3); WAIT_VM4(); }
        else                  { WAIT_VM0(); }
        RAW_BARRIER();                          // all waves' tile-kt loads landed
        const int bi = kt % 3;
        short8 af[4], bf[4];
#pragma unroll
        for (int mi = 0; mi < 4; ++mi)
            af[mi] = *(const short8*)&As[bi][(wr * 64 + mi * 16 + (lane & 15)) * 32 + (lane >> 4) * 8];
#pragma unroll
        for (int ni = 0; ni < 4; ++ni)
            bf[ni] = *(const short8*)&Bs[bi][(wc * 64 + ni * 16 + (lane & 15)) * 32 + (lane >> 4) * 8];
        __builtin_amdgcn_s_setprio(1);
#pragma unroll
        for (int mi = 0; mi < 4; ++mi)
#pragma unroll
            for (int ni = 0; ni < 4; ++ni)
                acc[mi][ni] = MFMA16(af[mi], bf[ni], acc[mi][ni]);
        __builtin_amdgcn_s_setprio(0);
    }

    if (MODE == 2) {
        float bv[4];
#pragma unroll
        for (int ni = 0; ni < 4; ++ni) bv[ni] = bias[tn * 128 + wc * 64 + ni * 16 + (lane & 15)];
        float* Co = (float*)oK;
#pragma unroll
        for (int mi = 0; mi < 4; ++mi)
#pragma unroll
            for (int ni = 0; ni < 4; ++ni)
#pragma unroll
                for (int j = 0; j < 4; ++j) {
                    int m = tm * 128 + wr * 64 + mi * 16 + (lane >> 4) * 4 + j;
                    int n = tn * 128 + wc * 64 + ni * 16 + (lane & 15);
                    Co[(size_t)m * DI + n] = acc[mi][ni][j] + bv[ni];
                }
    } else {
        const int which = tn >> 3;                  // 0:K  1:Q(scaled)  2:V(transposed)
        if (which < 2) {
            unsigned short* Co = which ? oQ : oK;
            const float scl = which ? QSCALE : 1.0f;
#pragma unroll
            for (int mi = 0; mi < 4; ++mi)
#pragma unroll
                for (int ni = 0; ni < 4; ++ni)
#pragma unroll
                    for (int j = 0; j < 4; ++j) {
                        int m = tm * 128 + wr * 64 + mi * 16 + (lane >> 4) * 4 + j;
                        int n = (tn & 7) * 128 + wc * 64 + ni * 16 + (lane & 15);
                        Co[(((size_t)(m >> 11) * NH + (n >> 6)) * SQ + (m & 2047)) * HD + (n & 63)] =
                            f2bf(acc[mi][ni][j] * scl);
                    }
        } else {                                    // V^T: [B][H][D][S], 4 S-contig per lane
#pragma unroll
            for (int mi = 0; mi < 4; ++mi)
#pragma unroll
                for (int ni = 0; ni < 4; ++ni) {
                    uint2v pk;
                    pk[0] = cvtpk(acc[mi][ni][0], acc[mi][ni][1]);
                    pk[1] = cvtpk(acc[mi][ni][2], acc[mi][ni][3]);
                    int m = tm * 128 + wr * 64 + mi * 16 + (lane >> 4) * 4;
                    int n = (tn & 7) * 128 + wc * 64 + ni * 16 + (lane & 15);
                    *(uint2v*)&oV[(((size_t)(m >> 11) * NH + (n >> 6)) * HD + (n & 63)) * SQ + (m & 2047)] = pk;
                }
        }
    }
}

// ---------------------------------------------------------------- fused attention
// Swapped-QK^T 32x32, softmax in-register (T12), counted-vmcnt 3-buf pipeline (T3/T4),
// per-strip split accumulators for cross-strip ILP, MFMA-pipe denominator (ones row).
__global__ __launch_bounds__(256) void k_attn(const unsigned short* __restrict__ Q,
                                              const unsigned short* __restrict__ K,
                                              const unsigned short* __restrict__ Vt,
                                              unsigned short* __restrict__ ctx) {
    __shared__ __align__(16) unsigned short smem[24576];   // 48KB: K 3-buf | V 3-buf (O-scratch reuse)
    unsigned short* Ks = smem;            // [3][64*64]
    unsigned short* Vs = smem + 12288;    // [3][64*64]
    const int tid = threadIdx.x, lane = tid & 63, w = tid >> 6;
    const int hi = lane >> 5, l31 = lane & 31;

    // XCD-chunked swizzle: 512 blocks, 8 XCDs -> 4 consecutive bh per XCD (K/V L2-resident)
    const int wg = (blockIdx.x & 7) * 64 + (blockIdx.x >> 3);
    const int bh = wg >> 4;
    const int q0 = (wg & 15) * 128;

    const unsigned short* qh = Q  + (size_t)bh * SQ * HD;
    const unsigned short* kh = K  + (size_t)bh * SQ * HD;
    const unsigned short* vh = Vt + (size_t)bh * HD * SQ;

    // Q^T B-fragments: lane provides col q = l31, k(d) = ks*16 + hi*8 + 0..7
    short8 qf[4];
#pragma unroll
    for (int ks = 0; ks < 4; ++ks)
        qf[ks] = *(const short8*)(qh + (size_t)(q0 + w * 32 + l31) * HD + ks * 16 + hi * 8);

    short8 ones;
#pragma unroll
    for (int i = 0; i < 8; ++i) ones[i] = (short)0x3F80;   // bf16 1.0

    f32x16 oA[2] = {{0}, {0}};  // strip-0 O^T acc (split per strip for cross-strip ILP)
    f32x16 oB[2] = {{0}, {0}};  // strip-1 O^T acc
    f32x16 od = {};             // denominator acc (shared; off critical path)

    auto stage = [&](int kt, int bi) {          // 4 global_load_lds per thread
#pragma unroll
        for (int i = 0; i < 2; ++i) {
            int u = tid + i * 256;              // row = u>>3 (0..63), chunk = u&7
            int row = u >> 3, c = u & 7;
            int cs = c ^ (row & 7);             // inverse-swizzled global source chunk
            gload16(kh + (size_t)(kt * 64 + row) * HD + cs * 8, Ks + bi * 4096 + u * 8);
            gload16(vh + (size_t)row * SQ + kt * 64 + cs * 8, Vs + bi * 4096 + u * 8);
        }
    };

    stage(0, 0);
    for (int kt = 0; kt < SQ / 64; ++kt) {
        if (kt + 1 < SQ / 64) { stage(kt + 1, (kt + 1) % 3); WAIT_VM4(); }
        else                  { WAIT_VM0(); }
        RAW_BARRIER();                          // all waves' tile-kt loads landed
        const unsigned short* kb_ = Ks + (kt % 3) * 4096;
        const unsigned short* vb_ = Vs + (kt % 3) * 4096;

        // all fragment reads for BOTH 32-ktok strips up front
        short8 kf[2][4], vf[2][2][2];
#pragma unroll
        for (int kb = 0; kb < 2; ++kb)
#pragma unroll
            for (int ks = 0; ks < 4; ++ks) {
                int row = kb * 32 + l31;
                kf[kb][ks] = *(const short8*)&kb_[row * 64 + (((ks * 2 + hi) ^ (row & 7)) * 8)];
            }
#pragma unroll
        for (int kb = 0; kb < 2; ++kb)
#pragma unroll
            for (int ks2 = 0; ks2 < 2; ++ks2)
#pragma unroll
                for (int da = 0; da < 2; ++da) {
                    int row = da * 32 + l31;
                    vf[kb][ks2][da] = *(const short8*)&vb_[row * 64 + (((kb * 4 + ks2 * 2 + hi) ^ (row & 7)) * 8)];
                }

        // QK^T: two independent 4-chains (s0, s1)
        f32x16 s0 = {}, s1 = {};
        __builtin_amdgcn_s_setprio(1);
#pragma unroll
        for (int ks = 0; ks < 4; ++ks) s0 = MFMA32(kf[0][ks], qf[ks], s0);
#pragma unroll
        for (int ks = 0; ks < 4; ++ks) s1 = MFMA32(kf[1][ks], qf[ks], s1);
        __builtin_amdgcn_s_setprio(0);

        // softmax + pack, per strip (independent chains)
        float p0[16], p1[16];
#pragma unroll
        for (int r = 0; r < 16; ++r) p0[r] = fexp2(s0[r]);
#pragma unroll
        for (int r = 0; r < 16; ++r) p1[r] = fexp2(s1[r]);

        unsigned a0 = cvtpk(p0[0],  p0[1]),  a1 = cvtpk(p0[2],  p0[3]);
        unsigned a2 = cvtpk(p0[4],  p0[5]),  a3 = cvtpk(p0[6],  p0[7]);
        unsigned a4 = cvtpk(p0[8],  p0[9]),  a5 = cvtpk(p0[10], p0[11]);
        unsigned a6 = cvtpk(p0[12], p0[13]), a7 = cvtpk(p0[14], p0[15]);
        plswap(a0, a2); plswap(a1, a3); plswap(a4, a6); plswap(a5, a7);
        short8 pf0[2] = { pack4(a0, a1, a2, a3), pack4(a4, a5, a6, a7) };

        unsigned b0 = cvtpk(p1[0],  p1[1]),  b1 = cvtpk(p1[2],  p1[3]);
        unsigned b2 = cvtpk(p1[4],  p1[5]),  b3 = cvtpk(p1[6],  p1[7]);
        unsigned b4 = cvtpk(p1[8],  p1[9]),  b5 = cvtpk(p1[10], p1[11]);
        unsigned b6 = cvtpk(p1[12], p1[13]), b7 = cvtpk(p1[14], p1[15]);
        plswap(b0, b2); plswap(b1, b3); plswap(b4, b6); plswap(b5, b7);
        short8 pf1[2] = { pack4(b0, b1, b2, b3), pack4(b4, b5, b6, b7) };

        // PV + denominator: strip-split accumulators
        __builtin_amdgcn_s_setprio(1);
#pragma unroll
        for (int ks2 = 0; ks2 < 2; ++ks2) {
#pragma unroll
            for (int da = 0; da < 2; ++da)
                oA[da] = MFMA32(vf[0][ks2][da], pf0[ks2], oA[da]);
            od = MFMA32(ones, pf0[ks2], od);
        }
#pragma unroll
        for (int ks2 = 0; ks2 < 2; ++ks2) {
#pragma unroll
            for (int da = 0; da < 2; ++da)
                oB[da] = MFMA32(vf[1][ks2][da], pf1[ks2], oB[da]);
            od = MFMA32(ones, pf1[ks2], od);
        }
        __builtin_amdgcn_s_setprio(0);
    }

    __syncthreads();                             // staging/frag reads done; reuse smem for O^T transpose

    float inv = 1.0f / od[0];                    // full denominator for q = l31 (all regs equal)

    unsigned short* osc = smem + w * 2304;       // per-wave [32 q][72] ushort (144B rows, 16B-aligned)
#pragma unroll
    for (int da = 0; da < 2; ++da)
#pragma unroll
        for (int g = 0; g < 4; ++g) {
            f32x16 om;
#pragma unroll
            for (int j = 0; j < 4; ++j) om[4 * g + j] = oA[da][4 * g + j] + oB[da][4 * g + j];
            uint2v pk;
            pk[0] = cvtpk(om[4 * g]     * inv, om[4 * g + 1] * inv);
            pk[1] = cvtpk(om[4 * g + 2] * inv, om[4 * g + 3] * inv);
            int d = da * 32 + 8 * g + 4 * hi;    // 4 consecutive d
            *(uint2v*)&osc[l31 * 72 + d] = pk;
        }
    __syncthreads();

    const int b = bh >> 4, h = bh & 15;
#pragma unroll
    for (int rr = 0; rr < 4; ++rr) {
        int qrow = rr * 8 + (lane >> 3), ck = lane & 7;
        int4v vv = *(const int4v*)&osc[qrow * 72 + ck * 8];
        *(int4v*)&ctx[((size_t)(b * SQ + q0 + w * 32 + qrow)) * DI + h * 64 + ck * 8] = vv;
    }
}

// ---------------------------------------------------------------- launch
extern "C" void kernel_launch(void* const* d_in, const int* in_sizes, int n_in,
                              void* d_out, int out_size, void* d_ws, size_t ws_size,
                              hipStream_t stream) {
    const float* x  = (const float*)d_in[0];
    const float* Wq = (const float*)d_in[1];
    const float* Wk = (const float*)d_in[2];
    const float* Wv = (const float*)d_in[3];
    const float* Wo = (const float*)d_in[4];
    const float* bo = (const float*)d_in[5];

    char* ws = (char*)d_ws;
    unsigned short* xb   = (unsigned short*)(ws);                 //  8 MB  x bf16
    unsigned short* Wall = (unsigned short*)(ws + (8u  << 20));   //  6 MB  [Wq|Wk|Wv]^T bf16
    unsigned short* Wot  = (unsigned short*)(ws + (14u << 20));   //  2 MB  Wo^T bf16
    unsigned short* Qh   = (unsigned short*)(ws + (16u << 20));   //  8 MB  queries (= x@Wk, pre-scaled)
    unsigned short* Kh   = (unsigned short*)(ws + (24u << 20));   //  8 MB  keys    (= x@Wq)
    unsigned short* Vt   = (unsigned short*)(ws + (32u << 20));   //  8 MB  values^T
    unsigned short* ctx  = (unsigned short*)(ws + (40u << 20));   //  8 MB

    k_cvt_bf16<<<2048, 256, 0, stream>>>(x, xb);
    k_transpose_w4<<<dim3(32, 32, 4), dim3(32, 8), 0, stream>>>(
        Wq, Wk, Wv, Wo, Wall, Wall + (1u << 20), Wall + (2u << 20), Wot);

    // fused QKV: keys = x@Wq (which 0), queries = x@Wk scaled (which 1), values^T = x@Wv (which 2)
    k_gemm<0><<<dim3(24, 32), 256, 0, stream>>>(xb, Wall, Kh, Qh, Vt, nullptr);

    k_attn<<<dim3(512), 256, 0, stream>>>(Qh, Kh, Vt, ctx);

    k_gemm<2><<<dim3(8, 32), 256, 0, stream>>>(ctx, Wot, (unsigned short*)d_out, nullptr, nullptr, bo);
}